// Round 1
// 729.908 us; speedup vs baseline: 1.0587x; 1.0587x over previous
//
#include <hip/hip_runtime.h>

// Attention_2035814498461 on MI355X (gfx950).
// B=2 N=2048 C=1024 H=16 hd=64, causal mask, outputs (x fp32, attn fp32).
// bf16 MFMA everywhere; two-pass online-normalization attention.
// This revision (vs 773us baseline):
//  - attn: XOR-swizzled K/V/Q LDS (pre-swizzled global source, swizzled read;
//    gll16 dest stays linear) -> b128 reads go 16-lanes/bank-quad -> 8 (optimal)
//  - attn: causal pairing (q-tiles p and 31-p per block) -> uniform 33
//    chunk-iters/block, kf/vf shared by both chunks, 512 blocks = 2/CU resident
//  - attn: K/V double-buffered, prefetch next tile before compute, ONE barrier
//    per iteration -> staging latency hidden
//  - attn: p_s padded to stride 72 (16B-aligned) -> kills p round-trip conflicts
//  - s_setprio(1) around MFMA clusters (T5, attn-positive)

typedef unsigned short u16;
typedef unsigned int u32;
typedef __attribute__((ext_vector_type(8))) short s16x8;
typedef __attribute__((ext_vector_type(4))) float f32x4;
typedef __attribute__((ext_vector_type(4))) u16 u16x4;

#define AS1 __attribute__((address_space(1)))
#define AS3 __attribute__((address_space(3)))

static __device__ __forceinline__ u16 f2bf(float f) {
  u32 u = __builtin_bit_cast(u32, f);
  u = (u + 0x7fffu + ((u >> 16) & 1u)) >> 16;
  return (u16)u;
}

static __device__ __forceinline__ void gll16(const u16* g, u16* l) {
  // async global->LDS, 16B per lane; LDS dest must be wave-uniform base + lane*16
  __builtin_amdgcn_global_load_lds((const AS1 u32*)g, (AS3 u32*)l, 16, 0, 0);
}

static __device__ __forceinline__ f32x4 mfma_bf16(s16x8 a, s16x8 b, f32x4 c) {
  return __builtin_amdgcn_mfma_f32_16x16x32_bf16(a, b, c, 0, 0, 0);
}

// ---------------- cast fp32 -> bf16 ----------------
__global__ __launch_bounds__(256) void cast_kernel(const float* __restrict__ in,
                                                   u16* __restrict__ out, int n4) {
  int i = blockIdx.x * 256 + threadIdx.x;
  if (i < n4) {
    f32x4 v = ((const f32x4*)in)[i];
    u16x4 o = { f2bf(v.x), f2bf(v.y), f2bf(v.z), f2bf(v.w) };
    ((u16x4*)out)[i] = o;
  }
}

// ---------------- shared 128x128 BT-GEMM core, K=1024 (unchanged) ----------------
static __device__ __forceinline__ void gemm_core_1024(
    const u16* __restrict__ A, const u16* __restrict__ Bm,
    int m0, int n0, int t, u16* a_s, u16* b_s, f32x4 acc[4][4]) {
  const int lane = t & 63;
  const int w = t >> 6;
  const int wm = (w & 1) * 64, wn = (w >> 1) * 64;
  const int lrow = lane & 15, lq = lane >> 4;
  const int r0 = t >> 2;          // staging row 0..63
  const int c0 = (t & 3) * 8;     // staging col (elements)

  for (int kt = 0; kt < 1024; kt += 32) {
    __syncthreads();
    gll16(A  + (size_t)(m0 + r0)      * 1024 + kt + c0, &a_s[(size_t)t * 8]);
    gll16(A  + (size_t)(m0 + r0 + 64) * 1024 + kt + c0, &a_s[(size_t)(t + 256) * 8]);
    gll16(Bm + (size_t)(n0 + r0)      * 1024 + kt + c0, &b_s[(size_t)t * 8]);
    gll16(Bm + (size_t)(n0 + r0 + 64) * 1024 + kt + c0, &b_s[(size_t)(t + 256) * 8]);
    __syncthreads();
    s16x8 af[4], bfr[4];
#pragma unroll
    for (int x = 0; x < 4; x++) af[x]  = *(const s16x8*)&a_s[(wm + x*16 + lrow)*32 + lq*8];
#pragma unroll
    for (int x = 0; x < 4; x++) bfr[x] = *(const s16x8*)&b_s[(wn + x*16 + lrow)*32 + lq*8];
#pragma unroll
    for (int tm = 0; tm < 4; tm++)
#pragma unroll
      for (int tn = 0; tn < 4; tn++)
        acc[tm][tn] = mfma_bf16(af[tm], bfr[tn], acc[tm][tn]);
  }
}

// ---------------- QKV projection (unchanged) ----------------
__global__ __launch_bounds__(256) void gemm_qkv_kernel(
    const u16* __restrict__ qb, const u16* __restrict__ kb, const u16* __restrict__ vb,
    const u16* __restrict__ wb, u16* __restrict__ Qh, u16* __restrict__ Kh,
    u16* __restrict__ Vt) {
  __shared__ u16 a_s[128*32], b_s[128*32];
  const int mode = blockIdx.z;
  const u16* A = (mode == 0) ? qb : (mode == 1) ? kb : vb;
  const u16* Bm = wb + (size_t)mode * (1024 * 1024);
  const int m0 = blockIdx.y * 128, n0 = blockIdx.x * 128;
  const int t = threadIdx.x;
  f32x4 acc[4][4];
  const f32x4 Z = {0.f, 0.f, 0.f, 0.f};
#pragma unroll
  for (int i = 0; i < 4; i++)
#pragma unroll
    for (int j = 0; j < 4; j++) acc[i][j] = Z;

  gemm_core_1024(A, Bm, m0, n0, t, a_s, b_s, acc);

  const int lane = t & 63, w = t >> 6;
  const int wm = (w & 1) * 64, wn = (w >> 1) * 64;
  const int lrow = lane & 15, lq = lane >> 4;
#pragma unroll
  for (int tm = 0; tm < 4; tm++) {
#pragma unroll
    for (int tn = 0; tn < 4; tn++) {
      const int ng = n0 + wn + tn * 16 + lrow;
      const int h = ng >> 6, d = ng & 63;
#pragma unroll
      for (int i = 0; i < 4; i++) {
        const int mg = m0 + wm + tm * 16 + lq * 4 + i;
        const int b = mg >> 11, s = mg & 2047;
        const float v = acc[tm][tn][i];
        if (mode == 0)
          Qh[((size_t)(b * 16 + h) * 2048 + s) * 64 + d] = f2bf(v * 0.125f);
        else if (mode == 1)
          Kh[((size_t)(b * 16 + h) * 2048 + s) * 64 + d] = f2bf(v);
        else
          Vt[((size_t)(b * 16 + h) * 64 + d) * 2048 + s] = f2bf(v);
      }
    }
  }
}

// ---------------- output projection (unchanged) ----------------
__global__ __launch_bounds__(256) void gemm_proj_kernel(
    const u16* __restrict__ xatt, const u16* __restrict__ pwb,
    const float* __restrict__ bias, float* __restrict__ out) {
  __shared__ u16 a_s[128*32], b_s[128*32];
  const int m0 = blockIdx.y * 128, n0 = blockIdx.x * 128;
  const int t = threadIdx.x;
  f32x4 acc[4][4];
  const f32x4 Z = {0.f, 0.f, 0.f, 0.f};
#pragma unroll
  for (int i = 0; i < 4; i++)
#pragma unroll
    for (int j = 0; j < 4; j++) acc[i][j] = Z;

  gemm_core_1024(xatt, pwb, m0, n0, t, a_s, b_s, acc);

  const int lane = t & 63, w = t >> 6;
  const int wm = (w & 1) * 64, wn = (w >> 1) * 64;
  const int lrow = lane & 15, lq = lane >> 4;
#pragma unroll
  for (int tn = 0; tn < 4; tn++) {
    const int ng = n0 + wn + tn * 16 + lrow;
    const float bv = bias[ng];
#pragma unroll
    for (int tm = 0; tm < 4; tm++) {
#pragma unroll
      for (int i = 0; i < 4; i++) {
        const int mg = m0 + wm + tm * 16 + lq * 4 + i;
        out[(size_t)mg * 1024 + ng] = acc[tm][tn][i] + bv;
      }
    }
  }
}

// ---------------- fused causal attention (paired + swizzled + dbuf) ----------------
// Block = pair of q-tiles {p*64, (31-p)*64} x one bh. Uniform 33 chunk-tile-iters.
// LDS rows are 64 bf16 = 128B; fragment reads XOR-swizzle the 16B chunk index
// with (row&7); staging pre-applies the same XOR on the per-lane GLOBAL source
// so the gll16 LDS dest stays linear (both-sides involution, guide rule 21).

static __device__ __forceinline__ void qk_tile(const s16x8 qf[2], const s16x8 kf[4][2],
                                               f32x4 sacc[4]) {
  const f32x4 Z = {0.f, 0.f, 0.f, 0.f};
#pragma unroll
  for (int tn = 0; tn < 4; tn++) {
    sacc[tn] = Z;
#pragma unroll
    for (int kq = 0; kq < 2; kq++)
      sacc[tn] = mfma_bf16(qf[kq], kf[tn][kq], sacc[tn]);
  }
}

static __device__ __forceinline__ void expsum_tile(const f32x4 sacc[4], bool diag,
                                                   int lrow, int rbase, float l_acc[4]) {
  float part[4] = {0.f, 0.f, 0.f, 0.f};
#pragma unroll
  for (int tn = 0; tn < 4; tn++)
#pragma unroll
    for (int i = 0; i < 4; i++) {
      const bool ok = !diag || (tn * 16 + lrow <= rbase + i);
      part[i] += ok ? __expf(sacc[tn][i]) : 0.f;
    }
#pragma unroll
  for (int i = 0; i < 4; i++) {
    float s = part[i];
    s += __shfl_xor(s, 1, 16);
    s += __shfl_xor(s, 2, 16);
    s += __shfl_xor(s, 4, 16);
    s += __shfl_xor(s, 8, 16);
    l_acc[i] += s;
  }
}

static __device__ __forceinline__ void p_tile(const f32x4 sacc[4], bool diag, int lrow,
                                              int lq, int w, const float inv_l[4],
                                              float* __restrict__ abase, u16* p_w,
                                              s16x8 pf[2]) {
#pragma unroll
  for (int tn = 0; tn < 4; tn++)
#pragma unroll
    for (int i = 0; i < 4; i++) {
      const int rl = lq * 4 + i;
      const bool ok = !diag || (tn * 16 + lrow <= w * 16 + rl);
      const float pv = ok ? __expf(sacc[tn][i]) * inv_l[i] : 0.f;
      abase[(size_t)rl * 2048 + tn * 16 + lrow] = pv;
      p_w[rl * 72 + tn * 16 + lrow] = f2bf(pv);   // stride 72: padded, 16B-aligned rows
    }
#pragma unroll
  for (int kq = 0; kq < 2; kq++)
    pf[kq] = *(const s16x8*)&p_w[lrow * 72 + kq * 32 + lq * 8];
}

__global__ __launch_bounds__(256) void attn_kernel(
    const u16* __restrict__ Qh, const u16* __restrict__ Kh, const u16* __restrict__ Vt,
    float* __restrict__ attn, u16* __restrict__ xatt, const int* __restrict__ use_mask_p) {
  // 50 KB LDS: K dbuf (16K) | Q-then-V dbuf (16K) | P tiles per wave x chunk (18K)
  __shared__ u16 smem[8192 + 8192 + 8 * 16 * 72];
  u16* k_s = smem;            // [2][64*64]
  u16* vq  = smem + 8192;     // Q chunks A,B at start; later V double buffer [2][64*64]
  u16* p_s = smem + 16384;    // [4 waves][2 chunks][16*72]

  const int bh = blockIdx.y;
  const int p  = blockIdx.x;            // pair index 0..15
  const int t = threadIdx.x;
  const int lane = t & 63, w = t >> 6;
  const int lrow = lane & 15, lq = lane >> 4;
  const int use_mask = *use_mask_p;

  const int q0[2] = { p * 64, (31 - p) * 64 };
  const int Tc[2] = { use_mask ? p : 31, use_mask ? 31 - p : 31 };
  const int Tmax  = Tc[1];              // >= Tc[0] always

  const int rs  = t >> 3;                         // staging row 0..31
  const int csw = (((t & 7) ^ (rs & 7)) * 8);     // pre-swizzled source col (elems)
  const int sk  = (lrow & 7) << 3;                // read-side swizzle key (elems)

  const u16* kg = Kh + (size_t)bh * (2048 * 64);
  const u16* vg = Vt + (size_t)bh * (64 * 2048);

  // ---- prologue: stage Q (both chunks) into vq, K[0] into k_s[0] ----
  {
    const u16* qgA = Qh + ((size_t)bh * 2048 + q0[0]) * 64;
    const u16* qgB = Qh + ((size_t)bh * 2048 + q0[1]) * 64;
    gll16(qgA + (size_t)rs * 64 + csw,        &vq[t * 8]);
    gll16(qgA + (size_t)(rs + 32) * 64 + csw, &vq[(t + 256) * 8]);
    gll16(qgB + (size_t)rs * 64 + csw,        &vq[4096 + t * 8]);
    gll16(qgB + (size_t)(rs + 32) * 64 + csw, &vq[4096 + (t + 256) * 8]);
    gll16(kg + (size_t)rs * 64 + csw,         &k_s[t * 8]);
    gll16(kg + (size_t)(rs + 32) * 64 + csw,  &k_s[(t + 256) * 8]);
  }
  __syncthreads();

  s16x8 qf[2][2];
  const int qrow = w * 16 + lrow;
#pragma unroll
  for (int kq = 0; kq < 2; kq++) {
    qf[0][kq] = *(const s16x8*)&vq[qrow * 64 + ((kq * 32 + lq * 8) ^ sk)];
    qf[1][kq] = *(const s16x8*)&vq[4096 + qrow * 64 + ((kq * 32 + lq * 8) ^ sk)];
  }

  const int rbase = w * 16 + lq * 4;

  // ---- pass 1: row sums l (K double-buffered, one barrier/iter) ----
  float l_acc[2][4];
#pragma unroll
  for (int c = 0; c < 2; c++)
#pragma unroll
    for (int i = 0; i < 4; i++) l_acc[c][i] = 0.f;

  for (int tt = 0; tt <= Tmax; tt++) {
    const int cur = tt & 1;
    if (tt < Tmax) {
      gll16(kg + (size_t)((tt + 1) * 64 + rs) * 64 + csw,      &k_s[(cur ^ 1) * 4096 + t * 8]);
      gll16(kg + (size_t)((tt + 1) * 64 + rs + 32) * 64 + csw, &k_s[(cur ^ 1) * 4096 + (t + 256) * 8]);
    }
    s16x8 kf[4][2];
#pragma unroll
    for (int tn = 0; tn < 4; tn++)
#pragma unroll
      for (int kq = 0; kq < 2; kq++)
        kf[tn][kq] = *(const s16x8*)&k_s[cur * 4096 + (tn * 16 + lrow) * 64 + ((kq * 32 + lq * 8) ^ sk)];
    f32x4 sacc[4];
    __builtin_amdgcn_s_setprio(1);
    qk_tile(qf[1], kf, sacc);
    __builtin_amdgcn_s_setprio(0);
    expsum_tile(sacc, use_mask && (tt == Tc[1]), lrow, rbase, l_acc[1]);
    if (tt <= Tc[0]) {
      __builtin_amdgcn_s_setprio(1);
      qk_tile(qf[0], kf, sacc);
      __builtin_amdgcn_s_setprio(0);
      expsum_tile(sacc, use_mask && (tt == Tc[0]), lrow, rbase, l_acc[0]);
    }
    __syncthreads();
  }

  float inv_l[2][4];
#pragma unroll
  for (int c = 0; c < 2; c++)
#pragma unroll
    for (int i = 0; i < 4; i++) inv_l[c][i] = 1.0f / l_acc[c][i];

  // ---- pass 2: P write + O = P@V (K and V double-buffered) ----
  f32x4 oacc[2][4];
  const f32x4 Z = {0.f, 0.f, 0.f, 0.f};
#pragma unroll
  for (int c = 0; c < 2; c++)
#pragma unroll
    for (int i = 0; i < 4; i++) oacc[c][i] = Z;

  // stage K[0], V[0] (q in vq is dead: qf lives in registers)
  gll16(kg + (size_t)rs * 64 + csw,          &k_s[t * 8]);
  gll16(kg + (size_t)(rs + 32) * 64 + csw,   &k_s[(t + 256) * 8]);
  gll16(vg + (size_t)rs * 2048 + csw,        &vq[t * 8]);
  gll16(vg + (size_t)(rs + 32) * 2048 + csw, &vq[(t + 256) * 8]);
  __syncthreads();

  for (int tt = 0; tt <= Tmax; tt++) {
    const int cur = tt & 1;
    if (tt < Tmax) {
      gll16(kg + (size_t)((tt + 1) * 64 + rs) * 64 + csw,        &k_s[(cur ^ 1) * 4096 + t * 8]);
      gll16(kg + (size_t)((tt + 1) * 64 + rs + 32) * 64 + csw,   &k_s[(cur ^ 1) * 4096 + (t + 256) * 8]);
      gll16(vg + (size_t)rs * 2048 + (tt + 1) * 64 + csw,        &vq[(cur ^ 1) * 4096 + t * 8]);
      gll16(vg + (size_t)(rs + 32) * 2048 + (tt + 1) * 64 + csw, &vq[(cur ^ 1) * 4096 + (t + 256) * 8]);
    }
    const bool act0 = (tt <= Tc[0]);
    s16x8 kf[4][2];
#pragma unroll
    for (int tn = 0; tn < 4; tn++)
#pragma unroll
      for (int kq = 0; kq < 2; kq++)
        kf[tn][kq] = *(const s16x8*)&k_s[cur * 4096 + (tn * 16 + lrow) * 64 + ((kq * 32 + lq * 8) ^ sk)];

    f32x4 sacc1[4], sacc0[4];
    __builtin_amdgcn_s_setprio(1);
    qk_tile(qf[1], kf, sacc1);
    if (act0) qk_tile(qf[0], kf, sacc0);
    __builtin_amdgcn_s_setprio(0);

    s16x8 pf1[2], pf0[2];
    {
      float* abase = attn + ((size_t)(bh * 2048 + q0[1] + w * 16)) * 2048 + tt * 64;
      p_tile(sacc1, use_mask && (tt == Tc[1]), lrow, lq, w, inv_l[1], abase,
             p_s + (w * 2 + 1) * 1152, pf1);
    }
    if (act0) {
      float* abase = attn + ((size_t)(bh * 2048 + q0[0] + w * 16)) * 2048 + tt * 64;
      p_tile(sacc0, use_mask && (tt == Tc[0]), lrow, lq, w, inv_l[0], abase,
             p_s + (w * 2 + 0) * 1152, pf0);
    }

    s16x8 vf[4][2];
#pragma unroll
    for (int td = 0; td < 4; td++)
#pragma unroll
      for (int kq = 0; kq < 2; kq++)
        vf[td][kq] = *(const s16x8*)&vq[cur * 4096 + (td * 16 + lrow) * 64 + ((kq * 32 + lq * 8) ^ sk)];

    __builtin_amdgcn_s_setprio(1);
#pragma unroll
    for (int td = 0; td < 4; td++)
#pragma unroll
      for (int kq = 0; kq < 2; kq++)
        oacc[1][td] = mfma_bf16(pf1[kq], vf[td][kq], oacc[1][td]);
    if (act0) {
#pragma unroll
      for (int td = 0; td < 4; td++)
#pragma unroll
        for (int kq = 0; kq < 2; kq++)
          oacc[0][td] = mfma_bf16(pf0[kq], vf[td][kq], oacc[0][td]);
    }
    __builtin_amdgcn_s_setprio(0);
    __syncthreads();
  }

  // ---- O -> xatt (B,N,C) bf16, both chunks ----
  const int b = bh >> 4, h = bh & 15;
#pragma unroll
  for (int c = 0; c < 2; c++)
#pragma unroll
    for (int td = 0; td < 4; td++)
#pragma unroll
      for (int i = 0; i < 4; i++) {
        const int row = q0[c] + w * 16 + lq * 4 + i;
        xatt[((size_t)(b * 2048 + row)) * 1024 + h * 64 + td * 16 + lrow] = f2bf(oacc[c][td][i]);
      }

  // ---- zero-fill masked upper region (balanced: 1984 cols/row-pair for all p) ----
  if (use_mask) {
    const f32x4 Z4 = {0.f, 0.f, 0.f, 0.f};
#pragma unroll
    for (int c = 0; c < 2; c++) {
      const int zc0 = q0[c] + 64;
      if (zc0 < 2048) {
        const int nzv = (2048 - zc0) >> 2;
        f32x4* zb = (f32x4*)(attn + ((size_t)bh * 2048 + q0[c]) * 2048 + zc0);
        const int row = t >> 2;
        for (int cc = (t & 3); cc < nzv; cc += 4)
          zb[(size_t)row * 512 + cc] = Z4;
      }
    }
  }
}

extern "C" void kernel_launch(void* const* d_in, const int* in_sizes, int n_in,
                              void* d_out, int out_size, void* d_ws, size_t ws_size,
                              hipStream_t stream) {
  const float* q      = (const float*)d_in[0];
  const float* k      = (const float*)d_in[1];
  const float* v      = (const float*)d_in[2];
  const float* qkv_w  = (const float*)d_in[3];
  const float* proj_w = (const float*)d_in[4];
  const float* proj_b = (const float*)d_in[5];
  const int*   use_mask = (const int*)d_in[6];

  const size_t MB = 1024 * 1024;
  char* ws = (char*)d_ws;
  u16* qb  = (u16*)(ws + 0 * MB);   // 8 MB (reused as xatt after QKV gemm)
  u16* kb  = (u16*)(ws + 8 * MB);   // 8 MB
  u16* vb  = (u16*)(ws + 16 * MB);  // 8 MB
  u16* wb  = (u16*)(ws + 24 * MB);  // 6 MB
  u16* pwb = (u16*)(ws + 30 * MB);  // 2 MB
  u16* Qh  = (u16*)(ws + 32 * MB);  // 8 MB
  u16* Kh  = (u16*)(ws + 40 * MB);  // 8 MB
  u16* Vt  = (u16*)(ws + 48 * MB);  // 8 MB
  u16* xat = qb;                    // qb dead after gemm_qkv; reuse

  float* out_x    = (float*)d_out;
  float* out_attn = out_x + (size_t)2 * 2048 * 1024;

  cast_kernel<<<4096, 256, 0, stream>>>(q, qb, 1048576);
  cast_kernel<<<4096, 256, 0, stream>>>(k, kb, 1048576);
  cast_kernel<<<4096, 256, 0, stream>>>(v, vb, 1048576);
  cast_kernel<<<3072, 256, 0, stream>>>(qkv_w, wb, 786432);
  cast_kernel<<<1024, 256, 0, stream>>>(proj_w, pwb, 262144);

  gemm_qkv_kernel<<<dim3(8, 32, 3), 256, 0, stream>>>(qb, kb, vb, wb, Qh, Kh, Vt);
  attn_kernel<<<dim3(16, 32), 256, 0, stream>>>(Qh, Kh, Vt, out_attn, xat, use_mask);
  gemm_proj_kernel<<<dim3(8, 32), 256, 0, stream>>>(xat, pwb, proj_b, out_x);
}

// Round 3
// 715.232 us; speedup vs baseline: 1.0805x; 1.0205x over previous
//
#include <hip/hip_runtime.h>

// Attention_2035814498461 on MI355X (gfx950).  [Round-2 resubmit: prior bench
// died with an infra-level "container failed twice" before executing; source
// audited for faults (bounds, alignment, barriers, graph-capture) - none found.]
// B=2 N=2048 C=1024 H=16 hd=64, causal mask, outputs (x fp32, attn fp32).
// bf16 MFMA everywhere; two-pass online-normalization attention.
// vs 730us:
//  - attn: __launch_bounds__(256,2) + chunk-sequential pass-2 (QK->P->PV per
//    chunk) to cut peak VGPR below 256 -> guarantee 2 blocks/CU occupancy
//  - attn: P round-trips through padded fp32 LDS tile; attn stores are now
//    full-128B-line global_store_dwordx4 (4/chunk instead of 16 scalar dword);
//    pf fragments rebuilt from the same fp32 values via f2bf (bit-identical)
//  - attn: zero-fill emits full 128B lines (8 lanes x 16B per row)
//  - casts merged into one kernel (saves 4 launches)

typedef unsigned short u16;
typedef unsigned int u32;
typedef __attribute__((ext_vector_type(8))) short s16x8;
typedef __attribute__((ext_vector_type(4))) float f32x4;
typedef __attribute__((ext_vector_type(4))) u16 u16x4;

#define AS1 __attribute__((address_space(1)))
#define AS3 __attribute__((address_space(3)))

static __device__ __forceinline__ u16 f2bf(float f) {
  u32 u = __builtin_bit_cast(u32, f);
  u = (u + 0x7fffu + ((u >> 16) & 1u)) >> 16;
  return (u16)u;
}

static __device__ __forceinline__ void gll16(const u16* g, u16* l) {
  // async global->LDS, 16B per lane; LDS dest must be wave-uniform base + lane*16
  __builtin_amdgcn_global_load_lds((const AS1 u32*)g, (AS3 u32*)l, 16, 0, 0);
}

static __device__ __forceinline__ f32x4 mfma_bf16(s16x8 a, s16x8 b, f32x4 c) {
  return __builtin_amdgcn_mfma_f32_16x16x32_bf16(a, b, c, 0, 0, 0);
}

// ---------------- merged cast fp32 -> bf16 ----------------
// regions (f32x4 units): q[0,1M) k[1M,2M) v[2M,3M) qkv_w[3M,3.75M) proj_w[3.75M,4M)
__global__ __launch_bounds__(256) void cast_all_kernel(
    const float* __restrict__ q, const float* __restrict__ k, const float* __restrict__ v,
    const float* __restrict__ qkv_w, const float* __restrict__ proj_w,
    u16* __restrict__ qb, u16* __restrict__ kb, u16* __restrict__ vb,
    u16* __restrict__ wb, u16* __restrict__ pwb) {
  int i = blockIdx.x * 256 + threadIdx.x;
  const float* src; u16* dst; int off;
  if (i < 1048576)       { src = q;      dst = qb;  off = i; }
  else if (i < 2097152)  { src = k;      dst = kb;  off = i - 1048576; }
  else if (i < 3145728)  { src = v;      dst = vb;  off = i - 2097152; }
  else if (i < 3932160)  { src = qkv_w;  dst = wb;  off = i - 3145728; }
  else if (i < 4194304)  { src = proj_w; dst = pwb; off = i - 3932160; }
  else return;
  f32x4 vv = ((const f32x4*)src)[off];
  u16x4 o = { f2bf(vv.x), f2bf(vv.y), f2bf(vv.z), f2bf(vv.w) };
  ((u16x4*)dst)[off] = o;
}

// ---------------- shared 128x128 BT-GEMM core, K=1024 (unchanged) ----------------
static __device__ __forceinline__ void gemm_core_1024(
    const u16* __restrict__ A, const u16* __restrict__ Bm,
    int m0, int n0, int t, u16* a_s, u16* b_s, f32x4 acc[4][4]) {
  const int lane = t & 63;
  const int w = t >> 6;
  const int wm = (w & 1) * 64, wn = (w >> 1) * 64;
  const int lrow = lane & 15, lq = lane >> 4;
  const int r0 = t >> 2;          // staging row 0..63
  const int c0 = (t & 3) * 8;     // staging col (elements)

  for (int kt = 0; kt < 1024; kt += 32) {
    __syncthreads();
    gll16(A  + (size_t)(m0 + r0)      * 1024 + kt + c0, &a_s[(size_t)t * 8]);
    gll16(A  + (size_t)(m0 + r0 + 64) * 1024 + kt + c0, &a_s[(size_t)(t + 256) * 8]);
    gll16(Bm + (size_t)(n0 + r0)      * 1024 + kt + c0, &b_s[(size_t)t * 8]);
    gll16(Bm + (size_t)(n0 + r0 + 64) * 1024 + kt + c0, &b_s[(size_t)(t + 256) * 8]);
    __syncthreads();
    s16x8 af[4], bfr[4];
#pragma unroll
    for (int x = 0; x < 4; x++) af[x]  = *(const s16x8*)&a_s[(wm + x*16 + lrow)*32 + lq*8];
#pragma unroll
    for (int x = 0; x < 4; x++) bfr[x] = *(const s16x8*)&b_s[(wn + x*16 + lrow)*32 + lq*8];
#pragma unroll
    for (int tm = 0; tm < 4; tm++)
#pragma unroll
      for (int tn = 0; tn < 4; tn++)
        acc[tm][tn] = mfma_bf16(af[tm], bfr[tn], acc[tm][tn]);
  }
}

// ---------------- QKV projection (unchanged) ----------------
__global__ __launch_bounds__(256) void gemm_qkv_kernel(
    const u16* __restrict__ qb, const u16* __restrict__ kb, const u16* __restrict__ vb,
    const u16* __restrict__ wb, u16* __restrict__ Qh, u16* __restrict__ Kh,
    u16* __restrict__ Vt) {
  __shared__ u16 a_s[128*32], b_s[128*32];
  const int mode = blockIdx.z;
  const u16* A = (mode == 0) ? qb : (mode == 1) ? kb : vb;
  const u16* Bm = wb + (size_t)mode * (1024 * 1024);
  const int m0 = blockIdx.y * 128, n0 = blockIdx.x * 128;
  const int t = threadIdx.x;
  f32x4 acc[4][4];
  const f32x4 Z = {0.f, 0.f, 0.f, 0.f};
#pragma unroll
  for (int i = 0; i < 4; i++)
#pragma unroll
    for (int j = 0; j < 4; j++) acc[i][j] = Z;

  gemm_core_1024(A, Bm, m0, n0, t, a_s, b_s, acc);

  const int lane = t & 63, w = t >> 6;
  const int wm = (w & 1) * 64, wn = (w >> 1) * 64;
  const int lrow = lane & 15, lq = lane >> 4;
#pragma unroll
  for (int tm = 0; tm < 4; tm++) {
#pragma unroll
    for (int tn = 0; tn < 4; tn++) {
      const int ng = n0 + wn + tn * 16 + lrow;
      const int h = ng >> 6, d = ng & 63;
#pragma unroll
      for (int i = 0; i < 4; i++) {
        const int mg = m0 + wm + tm * 16 + lq * 4 + i;
        const int b = mg >> 11, s = mg & 2047;
        const float v = acc[tm][tn][i];
        if (mode == 0)
          Qh[((size_t)(b * 16 + h) * 2048 + s) * 64 + d] = f2bf(v * 0.125f);
        else if (mode == 1)
          Kh[((size_t)(b * 16 + h) * 2048 + s) * 64 + d] = f2bf(v);
        else
          Vt[((size_t)(b * 16 + h) * 64 + d) * 2048 + s] = f2bf(v);
      }
    }
  }
}

// ---------------- output projection (unchanged) ----------------
__global__ __launch_bounds__(256) void gemm_proj_kernel(
    const u16* __restrict__ xatt, const u16* __restrict__ pwb,
    const float* __restrict__ bias, float* __restrict__ out) {
  __shared__ u16 a_s[128*32], b_s[128*32];
  const int m0 = blockIdx.y * 128, n0 = blockIdx.x * 128;
  const int t = threadIdx.x;
  f32x4 acc[4][4];
  const f32x4 Z = {0.f, 0.f, 0.f, 0.f};
#pragma unroll
  for (int i = 0; i < 4; i++)
#pragma unroll
    for (int j = 0; j < 4; j++) acc[i][j] = Z;

  gemm_core_1024(xatt, pwb, m0, n0, t, a_s, b_s, acc);

  const int lane = t & 63, w = t >> 6;
  const int wm = (w & 1) * 64, wn = (w >> 1) * 64;
  const int lrow = lane & 15, lq = lane >> 4;
#pragma unroll
  for (int tn = 0; tn < 4; tn++) {
    const int ng = n0 + wn + tn * 16 + lrow;
    const float bv = bias[ng];
#pragma unroll
    for (int tm = 0; tm < 4; tm++) {
#pragma unroll
      for (int i = 0; i < 4; i++) {
        const int mg = m0 + wm + tm * 16 + lq * 4 + i;
        out[(size_t)mg * 1024 + ng] = acc[tm][tn][i] + bv;
      }
    }
  }
}

// ---------------- fused causal attention ----------------
// Block = pair of q-tiles {p*64, (31-p)*64} x one bh. Uniform 33 chunk-iters.
// K/V in XOR-swizzled LDS (pre-swizzled global source, swizzled read).
// Pass 2 per chunk: QK -> P (fp32 LDS round-trip, coalesced 128B-line attn
// stores, pf rebuilt via f2bf) -> PV.  Chunks strictly sequential to keep
// VGPR peak < 256; __launch_bounds__(256,2) enforces 2 blocks/CU.

static __device__ __forceinline__ void qk_tile(const s16x8 qf[2], const s16x8 kf[4][2],
                                               f32x4 sacc[4]) {
  const f32x4 Z = {0.f, 0.f, 0.f, 0.f};
#pragma unroll
  for (int tn = 0; tn < 4; tn++) {
    sacc[tn] = Z;
#pragma unroll
    for (int kq = 0; kq < 2; kq++)
      sacc[tn] = mfma_bf16(qf[kq], kf[tn][kq], sacc[tn]);
  }
}

static __device__ __forceinline__ void expsum_tile(const f32x4 sacc[4], bool diag,
                                                   int lrow, int rbase, float l_acc[4]) {
  float part[4] = {0.f, 0.f, 0.f, 0.f};
#pragma unroll
  for (int tn = 0; tn < 4; tn++)
#pragma unroll
    for (int i = 0; i < 4; i++) {
      const bool ok = !diag || (tn * 16 + lrow <= rbase + i);
      part[i] += ok ? __expf(sacc[tn][i]) : 0.f;
    }
#pragma unroll
  for (int i = 0; i < 4; i++) {
    float s = part[i];
    s += __shfl_xor(s, 1, 16);
    s += __shfl_xor(s, 2, 16);
    s += __shfl_xor(s, 4, 16);
    s += __shfl_xor(s, 8, 16);
    l_acc[i] += s;
  }
}

// P phase: compute pv, stage to fp32 LDS tile (stride 68: write 2-way free,
// readbacks conflict-free), emit 4 full-128B-line dwordx4 attn stores, build pf.
static __device__ __forceinline__ void p_phase(const f32x4 sacc[4], bool diag,
                                               int lane, int lrow, int lq, int w,
                                               const float invl[4], float* pw,
                                               float* __restrict__ gb, s16x8 pf[2]) {
#pragma unroll
  for (int tn = 0; tn < 4; tn++)
#pragma unroll
    for (int i = 0; i < 4; i++) {
      const int rl = lq * 4 + i;
      const bool ok = !diag || (tn * 16 + lrow <= w * 16 + rl);
      const float pv = ok ? __expf(sacc[tn][i]) * invl[i] : 0.f;
      pw[rl * 68 + tn * 16 + lrow] = pv;
    }
  const int rr = lane >> 3, c8 = (lane & 7) * 4;
#pragma unroll
  for (int j = 0; j < 2; j++)
#pragma unroll
    for (int m = 0; m < 2; m++) {
      f32x4 vv = *(const f32x4*)&pw[(rr + 8 * j) * 68 + m * 32 + c8];
      *(f32x4*)&gb[(size_t)(rr + 8 * j) * 2048 + m * 32 + c8] = vv;
    }
#pragma unroll
  for (int kq = 0; kq < 2; kq++) {
    f32x4 lo = *(const f32x4*)&pw[lrow * 68 + kq * 32 + lq * 8];
    f32x4 hi = *(const f32x4*)&pw[lrow * 68 + kq * 32 + lq * 8 + 4];
    s16x8 r;
    r[0] = (short)f2bf(lo.x); r[1] = (short)f2bf(lo.y);
    r[2] = (short)f2bf(lo.z); r[3] = (short)f2bf(lo.w);
    r[4] = (short)f2bf(hi.x); r[5] = (short)f2bf(hi.y);
    r[6] = (short)f2bf(hi.z); r[7] = (short)f2bf(hi.w);
    pf[kq] = r;
  }
}

__global__ __launch_bounds__(256, 2) void attn_kernel(
    const u16* __restrict__ Qh, const u16* __restrict__ Kh, const u16* __restrict__ Vt,
    float* __restrict__ attn, u16* __restrict__ xatt, const int* __restrict__ use_mask_p) {
  // 49.4 KB LDS: K dbuf (16K) | Q-then-V dbuf (16K) | per-wave fp32 P tile (17K)
  __shared__ u16 smem[8192 + 8192];
  __shared__ float p32[4][16 * 68];
  u16* k_s = smem;            // [2][64*64]
  u16* vq  = smem + 8192;     // Q chunks A,B at start; later V double buffer

  const int bh = blockIdx.y;
  const int p  = blockIdx.x;            // pair index 0..15
  const int t = threadIdx.x;
  const int lane = t & 63, w = t >> 6;
  const int lrow = lane & 15, lq = lane >> 4;
  const int use_mask = *use_mask_p;

  const int q0[2] = { p * 64, (31 - p) * 64 };
  const int Tc[2] = { use_mask ? p : 31, use_mask ? 31 - p : 31 };
  const int Tmax  = Tc[1];              // >= Tc[0] always

  const int rs  = t >> 3;                         // staging row 0..31
  const int csw = (((t & 7) ^ (rs & 7)) * 8);     // pre-swizzled source col (elems)
  const int sk  = (lrow & 7) << 3;                // read-side swizzle key (elems)

  const u16* kg = Kh + (size_t)bh * (2048 * 64);
  const u16* vg = Vt + (size_t)bh * (64 * 2048);

  // ---- prologue: stage Q (both chunks) into vq, K[0] into k_s[0] ----
  {
    const u16* qgA = Qh + ((size_t)bh * 2048 + q0[0]) * 64;
    const u16* qgB = Qh + ((size_t)bh * 2048 + q0[1]) * 64;
    gll16(qgA + (size_t)rs * 64 + csw,        &vq[t * 8]);
    gll16(qgA + (size_t)(rs + 32) * 64 + csw, &vq[(t + 256) * 8]);
    gll16(qgB + (size_t)rs * 64 + csw,        &vq[4096 + t * 8]);
    gll16(qgB + (size_t)(rs + 32) * 64 + csw, &vq[4096 + (t + 256) * 8]);
    gll16(kg + (size_t)rs * 64 + csw,         &k_s[t * 8]);
    gll16(kg + (size_t)(rs + 32) * 64 + csw,  &k_s[(t + 256) * 8]);
  }
  __syncthreads();

  s16x8 qf[2][2];
  const int qrow = w * 16 + lrow;
#pragma unroll
  for (int kq = 0; kq < 2; kq++) {
    qf[0][kq] = *(const s16x8*)&vq[qrow * 64 + ((kq * 32 + lq * 8) ^ sk)];
    qf[1][kq] = *(const s16x8*)&vq[4096 + qrow * 64 + ((kq * 32 + lq * 8) ^ sk)];
  }

  const int rbase = w * 16 + lq * 4;

  // ---- pass 1: row sums l (K double-buffered, one barrier/iter) ----
  float l_acc[2][4];
#pragma unroll
  for (int c = 0; c < 2; c++)
#pragma unroll
    for (int i = 0; i < 4; i++) l_acc[c][i] = 0.f;

  for (int tt = 0; tt <= Tmax; tt++) {
    const int cur = tt & 1;
    if (tt < Tmax) {
      gll16(kg + (size_t)((tt + 1) * 64 + rs) * 64 + csw,      &k_s[(cur ^ 1) * 4096 + t * 8]);
      gll16(kg + (size_t)((tt + 1) * 64 + rs + 32) * 64 + csw, &k_s[(cur ^ 1) * 4096 + (t + 256) * 8]);
    }
    s16x8 kf[4][2];
#pragma unroll
    for (int tn = 0; tn < 4; tn++)
#pragma unroll
      for (int kq = 0; kq < 2; kq++)
        kf[tn][kq] = *(const s16x8*)&k_s[cur * 4096 + (tn * 16 + lrow) * 64 + ((kq * 32 + lq * 8) ^ sk)];
    f32x4 sacc[4];
    __builtin_amdgcn_s_setprio(1);
    qk_tile(qf[1], kf, sacc);
    __builtin_amdgcn_s_setprio(0);
    expsum_tile(sacc, use_mask && (tt == Tc[1]), lrow, rbase, l_acc[1]);
    if (tt <= Tc[0]) {
      __builtin_amdgcn_s_setprio(1);
      qk_tile(qf[0], kf, sacc);
      __builtin_amdgcn_s_setprio(0);
      expsum_tile(sacc, use_mask && (tt == Tc[0]), lrow, rbase, l_acc[0]);
    }
    __syncthreads();
  }

  float inv_l[2][4];
#pragma unroll
  for (int c = 0; c < 2; c++)
#pragma unroll
    for (int i = 0; i < 4; i++) inv_l[c][i] = 1.0f / l_acc[c][i];

  // ---- pass 2: P write + O = P@V (K and V double-buffered) ----
  f32x4 oacc[2][4];
  const f32x4 Z = {0.f, 0.f, 0.f, 0.f};
#pragma unroll
  for (int c = 0; c < 2; c++)
#pragma unroll
    for (int i = 0; i < 4; i++) oacc[c][i] = Z;

  // stage K[0], V[0] (q in vq is dead: qf lives in registers)
  gll16(kg + (size_t)rs * 64 + csw,          &k_s[t * 8]);
  gll16(kg + (size_t)(rs + 32) * 64 + csw,   &k_s[(t + 256) * 8]);
  gll16(vg + (size_t)rs * 2048 + csw,        &vq[t * 8]);
  gll16(vg + (size_t)(rs + 32) * 2048 + csw, &vq[(t + 256) * 8]);
  __syncthreads();

  float* pw = &p32[w][0];

  for (int tt = 0; tt <= Tmax; tt++) {
    const int cur = tt & 1;
    if (tt < Tmax) {
      gll16(kg + (size_t)((tt + 1) * 64 + rs) * 64 + csw,        &k_s[(cur ^ 1) * 4096 + t * 8]);
      gll16(kg + (size_t)((tt + 1) * 64 + rs + 32) * 64 + csw,   &k_s[(cur ^ 1) * 4096 + (t + 256) * 8]);
      gll16(vg + (size_t)rs * 2048 + (tt + 1) * 64 + csw,        &vq[(cur ^ 1) * 4096 + t * 8]);
      gll16(vg + (size_t)(rs + 32) * 2048 + (tt + 1) * 64 + csw, &vq[(cur ^ 1) * 4096 + (t + 256) * 8]);
    }
    const bool act0 = (tt <= Tc[0]);
    s16x8 kf[4][2];
#pragma unroll
    for (int tn = 0; tn < 4; tn++)
#pragma unroll
      for (int kq = 0; kq < 2; kq++)
        kf[tn][kq] = *(const s16x8*)&k_s[cur * 4096 + (tn * 16 + lrow) * 64 + ((kq * 32 + lq * 8) ^ sk)];
    s16x8 vf[4][2];
#pragma unroll
    for (int td = 0; td < 4; td++)
#pragma unroll
      for (int kq = 0; kq < 2; kq++)
        vf[td][kq] = *(const s16x8*)&vq[cur * 4096 + (td * 16 + lrow) * 64 + ((kq * 32 + lq * 8) ^ sk)];

    // ---- chunk 1 (always active) ----
    {
      f32x4 sacc[4];
      __builtin_amdgcn_s_setprio(1);
      qk_tile(qf[1], kf, sacc);
      __builtin_amdgcn_s_setprio(0);
      s16x8 pf[2];
      float* gb = attn + ((size_t)(bh * 2048 + q0[1] + w * 16)) * 2048 + tt * 64;
      p_phase(sacc, use_mask && (tt == Tc[1]), lane, lrow, lq, w, inv_l[1], pw, gb, pf);
      __builtin_amdgcn_s_setprio(1);
#pragma unroll
      for (int td = 0; td < 4; td++)
#pragma unroll
        for (int kq = 0; kq < 2; kq++)
          oacc[1][td] = mfma_bf16(pf[kq], vf[td][kq], oacc[1][td]);
      __builtin_amdgcn_s_setprio(0);
    }
    // ---- chunk 0 (active while tt <= Tc[0]) ----
    if (act0) {
      f32x4 sacc[4];
      __builtin_amdgcn_s_setprio(1);
      qk_tile(qf[0], kf, sacc);
      __builtin_amdgcn_s_setprio(0);
      s16x8 pf[2];
      float* gb = attn + ((size_t)(bh * 2048 + q0[0] + w * 16)) * 2048 + tt * 64;
      p_phase(sacc, use_mask && (tt == Tc[0]), lane, lrow, lq, w, inv_l[0], pw, gb, pf);
      __builtin_amdgcn_s_setprio(1);
#pragma unroll
      for (int td = 0; td < 4; td++)
#pragma unroll
        for (int kq = 0; kq < 2; kq++)
          oacc[0][td] = mfma_bf16(pf[kq], vf[td][kq], oacc[0][td]);
      __builtin_amdgcn_s_setprio(0);
    }
    __syncthreads();
  }

  // ---- O -> xatt (B,N,C) bf16, both chunks ----
  const int b = bh >> 4, h = bh & 15;
#pragma unroll
  for (int c = 0; c < 2; c++)
#pragma unroll
    for (int td = 0; td < 4; td++)
#pragma unroll
      for (int i = 0; i < 4; i++) {
        const int row = q0[c] + w * 16 + lq * 4 + i;
        xatt[((size_t)(b * 2048 + row)) * 1024 + h * 64 + td * 16 + lrow] = f2bf(oacc[c][td][i]);
      }

  // ---- zero-fill masked upper region: full 128B lines (8 lanes x 16B / row) ----
  if (use_mask) {
    const f32x4 Z4 = {0.f, 0.f, 0.f, 0.f};
    const int rr = t >> 3;          // 0..31
    const int c8 = (t & 7) * 4;     // float offset within 32-float chunk
#pragma unroll
    for (int c = 0; c < 2; c++) {
      const int zc0 = q0[c] + 64;
      if (zc0 < 2048) {
        const int n32 = (2048 - zc0) >> 5;   // 32-float (128B) chunks per row
        float* zb = attn + ((size_t)bh * 2048 + q0[c]) * 2048 + zc0;
        for (int j = 0; j < n32; j++) {
          *(f32x4*)&zb[(size_t)rr * 2048 + j * 32 + c8] = Z4;
          *(f32x4*)&zb[(size_t)(rr + 32) * 2048 + j * 32 + c8] = Z4;
        }
      }
    }
  }
}

extern "C" void kernel_launch(void* const* d_in, const int* in_sizes, int n_in,
                              void* d_out, int out_size, void* d_ws, size_t ws_size,
                              hipStream_t stream) {
  const float* q      = (const float*)d_in[0];
  const float* k      = (const float*)d_in[1];
  const float* v      = (const float*)d_in[2];
  const float* qkv_w  = (const float*)d_in[3];
  const float* proj_w = (const float*)d_in[4];
  const float* proj_b = (const float*)d_in[5];
  const int*   use_mask = (const int*)d_in[6];

  const size_t MB = 1024 * 1024;
  char* ws = (char*)d_ws;
  u16* qb  = (u16*)(ws + 0 * MB);   // 8 MB (reused as xatt after QKV gemm)
  u16* kb  = (u16*)(ws + 8 * MB);   // 8 MB
  u16* vb  = (u16*)(ws + 16 * MB);  // 8 MB
  u16* wb  = (u16*)(ws + 24 * MB);  // 6 MB
  u16* pwb = (u16*)(ws + 30 * MB);  // 2 MB
  u16* Qh  = (u16*)(ws + 32 * MB);  // 8 MB
  u16* Kh  = (u16*)(ws + 40 * MB);  // 8 MB
  u16* Vt  = (u16*)(ws + 48 * MB);  // 8 MB
  u16* xat = qb;                    // qb dead after gemm_qkv; reuse

  float* out_x    = (float*)d_out;
  float* out_attn = out_x + (size_t)2 * 2048 * 1024;

  cast_all_kernel<<<16384, 256, 0, stream>>>(q, k, v, qkv_w, proj_w, qb, kb, vb, wb, pwb);

  gemm_qkv_kernel<<<dim3(8, 32, 3), 256, 0, stream>>>(qb, kb, vb, wb, Qh, Kh, Vt);
  attn_kernel<<<dim3(16, 32), 256, 0, stream>>>(Qh, Kh, Vt, out_attn, xat, use_mask);
  gemm_proj_kernel<<<dim3(8, 32), 256, 0, stream>>>(xat, pwb, proj_b, out_x);
}